// Round 15
// baseline (570.719 us; speedup 1.0000x reference)
//
#include <hip/hip_runtime.h>

// GAT aggregate, FUSED — R15 SELF-PROFILING ROUND (R14 exact + REPS=3 loop).
// The fused kernel is idempotent, so repeating all tiles 3x inside ONE
// dispatch (~635us) pushes it above the ~480us harness fill kernels in the
// top-5 counter table, exposing FETCH/WRITE/hbm/VALU/occupancy for OUR code.
// Divide FETCH by 3 for per-pass bytes; compare vs 872 MB ideal.
//   fork: FETCH/3 ~1.3GB -> over-fetch real, attack bytes next;
//         FETCH/3 ~0.9GB + hbm>80% -> at roofline;
//         FETCH/3 ~0.9GB + hbm~60% -> dead time, attack occupancy.

constexpr int K    = 16;
constexpr int D    = 128;
constexpr int DOUT = 128;
constexpr int WT_PITCH = 136;   // bf16 Wt row pitch (shorts), 272B rows
constexpr int CT_PITCH = 132;   // f32 Ct row pitch (floats), 528B rows

typedef short bfrag  __attribute__((ext_vector_type(8)));
typedef float afrag  __attribute__((ext_vector_type(4)));

__device__ __forceinline__ unsigned short f2bf(float f) {
    union { float f; unsigned u; } v; v.f = f;
    const unsigned r = v.u + 0x7FFF + ((v.u >> 16) & 1);   // RNE
    return (unsigned short)(r >> 16);
}
__device__ __forceinline__ float bf2f(unsigned short b) {
    union { unsigned u; float f; } v; v.u = ((unsigned)b) << 16;
    return v.f;
}

__device__ __forceinline__ float wave_allsum(float x) {
    #pragma unroll
    for (int off = 32; off; off >>= 1)
        x += __shfl_xor(x, off);
    return x;
}

#define LOAD_NODE(vv, sv, nabs) do {                                          \
    const int n_ = (nabs);                                                    \
    const float* nbp_ = neigh_vecs + (size_t)n_ * (K * D) + 2 * lane;         \
    _Pragma("unroll")                                                         \
    for (int k = 0; k < K; ++k) vv[k] = *(const float2*)(nbp_ + (size_t)k * D); \
    sv = *(const float2*)(self_vecs + (size_t)n_ * D + 2 * lane);             \
} while (0)

#define CTX_NODE(vv, sv, row) do {                                            \
    float ss_ = sv.x * sv.x + sv.y * sv.y;                                    \
    float sc_[K];                                                             \
    _Pragma("unroll")                                                         \
    for (int k = 0; k < K; ++k) sc_[k] = sv.x * vv[k].x + sv.y * vv[k].y;     \
    ss_ = wave_allsum(ss_);                                                   \
    _Pragma("unroll")                                                         \
    for (int k = 0; k < K; ++k) sc_[k] = wave_allsum(sc_[k]);                 \
    float m_ = ss_;                                                           \
    _Pragma("unroll")                                                         \
    for (int k = 0; k < K; ++k) m_ = fmaxf(m_, sc_[k]);                       \
    float e_ = __expf(ss_ - m_);                                              \
    float sum_ = e_, cx_ = e_ * sv.x, cy_ = e_ * sv.y;                        \
    _Pragma("unroll")                                                         \
    for (int k = 0; k < K; ++k) {                                             \
        const float ek_ = __expf(sc_[k] - m_);                                \
        sum_ += ek_; cx_ += ek_ * vv[k].x; cy_ += ek_ * vv[k].y;              \
    }                                                                         \
    const float inv_ = 1.f / sum_;                                            \
    *(float2*)&Ct[buf][row][2 * lane] = make_float2(cx_ * inv_, cy_ * inv_);  \
} while (0)

__launch_bounds__(256, 3)
__global__ void gat_fused(const float* __restrict__ self_vecs,
                          const float* __restrict__ neigh_vecs,
                          const float* __restrict__ W,
                          float* __restrict__ out,
                          int n_tiles, int reps) {
    __shared__ __align__(16) unsigned short Wt[DOUT][WT_PITCH];   // 34.8 KiB
    __shared__ __align__(16) float Ct[2][16][CT_PITCH];           // 16.5 KiB

    const int tid = threadIdx.x;

    for (int e = tid; e < D * DOUT; e += blockDim.x) {
        const int k = e >> 7, m = e & 127;     // W row-major [k][dout]
        Wt[m][k] = f2bf(W[e]);
    }
    __syncthreads();

    const int lane = tid & 63;
    const int wid  = tid >> 6;
    const int nl   = lane & 15;
    const int kb   = lane >> 4;
    const int r0   = wid * 4;

    float2 vA[K], vB[K], sA, sB;
    int buf = 0;

    for (int rep = 0; rep < reps; ++rep) {
        int t = blockIdx.x;
        if (t < n_tiles) {
            LOAD_NODE(vA, sA, t * 16 + r0 + 0);
            LOAD_NODE(vB, sB, t * 16 + r0 + 1);
        }
        for (; t < n_tiles; t += gridDim.x, buf ^= 1) {
            const int node0 = t * 16;

            CTX_NODE(vA, sA, r0 + 0);
            LOAD_NODE(vA, sA, node0 + r0 + 2);
            CTX_NODE(vB, sB, r0 + 1);
            LOAD_NODE(vB, sB, node0 + r0 + 3);
            CTX_NODE(vA, sA, r0 + 2);
            CTX_NODE(vB, sB, r0 + 3);

            const int tn = t + gridDim.x;
            if (tn < n_tiles) {
                LOAD_NODE(vA, sA, tn * 16 + r0 + 0);
                LOAD_NODE(vB, sB, tn * 16 + r0 + 1);
            }

            __syncthreads();

            afrag acc[2];
            #pragma unroll
            for (int h = 0; h < 2; ++h)
                #pragma unroll
                for (int r4 = 0; r4 < 4; ++r4) acc[h][r4] = 0.f;

            #pragma unroll
            for (int kc = 0; kc < 4; ++kc) {
                const float* cp = &Ct[buf][nl][kc * 32 + kb * 8];
                const float4 c0 = *(const float4*)cp;
                const float4 c1 = *(const float4*)(cp + 4);
                const float cf[8] = {c0.x, c0.y, c0.z, c0.w, c1.x, c1.y, c1.z, c1.w};
                bfrag ch, cl;
                #pragma unroll
                for (int i = 0; i < 8; ++i) {
                    const unsigned short hh = f2bf(cf[i]);
                    ch[i] = (short)hh;
                    cl[i] = (short)f2bf(cf[i] - bf2f(hh));
                }
                #pragma unroll
                for (int h = 0; h < 2; ++h) {
                    const int nt = wid * 2 + h;
                    const bfrag a = *(const bfrag*)&Wt[nt * 16 + nl][kc * 32 + kb * 8];
                    acc[h] = __builtin_amdgcn_mfma_f32_16x16x32_bf16(a, ch, acc[h], 0, 0, 0);
                    acc[h] = __builtin_amdgcn_mfma_f32_16x16x32_bf16(a, cl, acc[h], 0, 0, 0);
                }
            }
            float* orow = out + (size_t)(node0 + nl) * DOUT + kb * 4;
            #pragma unroll
            for (int h = 0; h < 2; ++h) {
                const int nt = wid * 2 + h;
                *(float4*)(orow + nt * 16) =
                    make_float4(fmaxf(acc[h][0], 0.f), fmaxf(acc[h][1], 0.f),
                                fmaxf(acc[h][2], 0.f), fmaxf(acc[h][3], 0.f));
            }
        }
    }
}

extern "C" void kernel_launch(void* const* d_in, const int* in_sizes, int n_in,
                              void* d_out, int out_size, void* d_ws, size_t ws_size,
                              hipStream_t stream) {
    const float* self_vecs = (const float*)d_in[0];
    const float* neigh     = (const float*)d_in[1];
    const float* W         = (const float*)d_in[2];
    float* out = (float*)d_out;

    const int n_nodes = in_sizes[0] / D;   // 100000
    const int n_tiles = n_nodes / 16;      // 6250 exact

    const int tpb = 256;     // 4 waves
    const int blocks = 768;  // 3 blocks/CU x 256 CU (51.3 KiB LDS each)
    // REPS=3: single ~635us dispatch -> tops the counter table (probe round)
    gat_fused<<<dim3(blocks), dim3(tpb), 0, stream>>>(
        self_vecs, neigh, W, out, n_tiles, 3);
}

// Round 16
// 206.671 us; speedup vs baseline: 2.7615x; 2.7615x over previous
//
#include <hip/hip_runtime.h>

// GAT aggregate, FUSED (R16 = R14 structure at 512 threads): N=100000, K=16,
// D=128, DOUT=128, fp32. Per 16-node tile, one 512-thr block (8 waves): each
// wave computes 2 ctx rows (two-pass softmax, depth-2 load pipeline) into LDS
// Ct[buf], one barrier, then 1 MFMA output subtile (nt=wid) to d_out.
//
// R15 probe counters: hbm 33%, VALU 27%, MFMA 1%, occupancy 30%, conflicts
// 1.5% -> latency-bound at 12 waves/CU (LDS caps 3 blocks/CU; 256thr blocks).
// R16: same 51.3KiB LDS, 512-thr blocks -> 24 waves/CU (75%), 2x in-flight
// loads, shorter per-wave phase before each barrier. VGPR must stay <=85
// (6 waves/SIMD x 85 = 510 <= 512-reg file); R14 measured 84 with the BIGGER
// per-wave working set, so the 2-row variant fits.

constexpr int K    = 16;
constexpr int D    = 128;
constexpr int DOUT = 128;
constexpr int WT_PITCH = 136;   // bf16 Wt pitch (shorts): 272B rows -> 16 lanes spread 4-banks apart, 2-way max (free per m136)
constexpr int CT_PITCH = 132;   // f32 Ct pitch (floats), 528B rows

typedef short bfrag  __attribute__((ext_vector_type(8)));
typedef float afrag  __attribute__((ext_vector_type(4)));

__device__ __forceinline__ unsigned short f2bf(float f) {
    union { float f; unsigned u; } v; v.f = f;
    const unsigned r = v.u + 0x7FFF + ((v.u >> 16) & 1);   // RNE
    return (unsigned short)(r >> 16);
}
__device__ __forceinline__ float bf2f(unsigned short b) {
    union { unsigned u; float f; } v; v.u = ((unsigned)b) << 16;
    return v.f;
}

__device__ __forceinline__ float wave_allsum(float x) {
    #pragma unroll
    for (int off = 32; off; off >>= 1)
        x += __shfl_xor(x, off);
    return x;
}

#define LOAD_NODE(vv, sv, nabs) do {                                          \
    const int n_ = (nabs);                                                    \
    const float* nbp_ = neigh_vecs + (size_t)n_ * (K * D) + 2 * lane;         \
    _Pragma("unroll")                                                         \
    for (int k = 0; k < K; ++k) vv[k] = *(const float2*)(nbp_ + (size_t)k * D); \
    sv = *(const float2*)(self_vecs + (size_t)n_ * D + 2 * lane);             \
} while (0)

#define CTX_NODE(vv, sv, row) do {                                            \
    float ss_ = sv.x * sv.x + sv.y * sv.y;                                    \
    float sc_[K];                                                             \
    _Pragma("unroll")                                                         \
    for (int k = 0; k < K; ++k) sc_[k] = sv.x * vv[k].x + sv.y * vv[k].y;     \
    ss_ = wave_allsum(ss_);                                                   \
    _Pragma("unroll")                                                         \
    for (int k = 0; k < K; ++k) sc_[k] = wave_allsum(sc_[k]);                 \
    float m_ = ss_;                                                           \
    _Pragma("unroll")                                                         \
    for (int k = 0; k < K; ++k) m_ = fmaxf(m_, sc_[k]);                       \
    float e_ = __expf(ss_ - m_);                                              \
    float sum_ = e_, cx_ = e_ * sv.x, cy_ = e_ * sv.y;                        \
    _Pragma("unroll")                                                         \
    for (int k = 0; k < K; ++k) {                                             \
        const float ek_ = __expf(sc_[k] - m_);                                \
        sum_ += ek_; cx_ += ek_ * vv[k].x; cy_ += ek_ * vv[k].y;              \
    }                                                                         \
    const float inv_ = 1.f / sum_;                                            \
    *(float2*)&Ct[buf][row][2 * lane] = make_float2(cx_ * inv_, cy_ * inv_);  \
} while (0)

__launch_bounds__(512, 3)
__global__ void gat_fused(const float* __restrict__ self_vecs,
                          const float* __restrict__ neigh_vecs,
                          const float* __restrict__ W,
                          float* __restrict__ out,
                          int n_tiles) {
    __shared__ __align__(16) unsigned short Wt[DOUT][WT_PITCH];   // 34.8 KiB
    __shared__ __align__(16) float Ct[2][16][CT_PITCH];           // 16.5 KiB

    const int tid = threadIdx.x;

    // ---- stage W^T as bf16 (R10-verbatim) ----
    for (int e = tid; e < D * DOUT; e += blockDim.x) {
        const int k = e >> 7, m = e & 127;     // W row-major [k][dout]
        Wt[m][k] = f2bf(W[e]);
    }
    __syncthreads();

    const int lane = tid & 63;
    const int wid  = tid >> 6;    // 0..7
    const int nl   = lane & 15;
    const int kb   = lane >> 4;
    const int r0   = wid * 2;     // this wave's 2 rows in the tile

    float2 vA[K], vB[K], sA, sB;

    int buf = 0;
    int t = blockIdx.x;
    if (t < n_tiles) {                       // prologue: both rows in flight
        LOAD_NODE(vA, sA, t * 16 + r0 + 0);
        LOAD_NODE(vB, sB, t * 16 + r0 + 1);
    }
    for (; t < n_tiles; t += gridDim.x, buf ^= 1) {
        const int node0 = t * 16;

        // ---- ctx: 2 rows, pipelined; prefetch next tile before the barrier ----
        CTX_NODE(vA, sA, r0 + 0);
        CTX_NODE(vB, sB, r0 + 1);
        const int tn = t + gridDim.x;
        if (tn < n_tiles) {
            LOAD_NODE(vA, sA, tn * 16 + r0 + 0);
            LOAD_NODE(vB, sB, tn * 16 + r0 + 1);
        }

        __syncthreads();   // Ct[buf] complete (dbuf -> only barrier per tile)

        // ---- MFMA (R10-verbatim layouts): this wave does nt = wid ----
        afrag acc;
        #pragma unroll
        for (int r4 = 0; r4 < 4; ++r4) acc[r4] = 0.f;

        #pragma unroll
        for (int kc = 0; kc < 4; ++kc) {
            const float* cp = &Ct[buf][nl][kc * 32 + kb * 8];
            const float4 c0 = *(const float4*)cp;
            const float4 c1 = *(const float4*)(cp + 4);
            const float cf[8] = {c0.x, c0.y, c0.z, c0.w, c1.x, c1.y, c1.z, c1.w};
            bfrag ch, cl;
            #pragma unroll
            for (int i = 0; i < 8; ++i) {
                const unsigned short hh = f2bf(cf[i]);
                ch[i] = (short)hh;
                cl[i] = (short)f2bf(cf[i] - bf2f(hh));
            }
            const bfrag a = *(const bfrag*)&Wt[wid * 16 + nl][kc * 32 + kb * 8];
            acc = __builtin_amdgcn_mfma_f32_16x16x32_bf16(a, ch, acc, 0, 0, 0);
            acc = __builtin_amdgcn_mfma_f32_16x16x32_bf16(a, cl, acc, 0, 0, 0);
        }
        // D: col=lane&15=node, row=(lane>>4)*4+r=outcol (m89-verified)
        float* orow = out + (size_t)(node0 + nl) * DOUT + kb * 4;
        *(float4*)(orow + wid * 16) =
            make_float4(fmaxf(acc[0], 0.f), fmaxf(acc[1], 0.f),
                        fmaxf(acc[2], 0.f), fmaxf(acc[3], 0.f));
    }
}

extern "C" void kernel_launch(void* const* d_in, const int* in_sizes, int n_in,
                              void* d_out, int out_size, void* d_ws, size_t ws_size,
                              hipStream_t stream) {
    const float* self_vecs = (const float*)d_in[0];
    const float* neigh     = (const float*)d_in[1];
    const float* W         = (const float*)d_in[2];
    float* out = (float*)d_out;

    const int n_nodes = in_sizes[0] / D;   // 100000
    const int n_tiles = n_nodes / 16;      // 6250 exact

    const int tpb = 512;     // 8 waves
    const int blocks = 768;  // 3 blocks/CU x 256 CU (51.3 KiB LDS each) -> 24 waves/CU
    gat_fused<<<dim3(blocks), dim3(tpb), 0, stream>>>(
        self_vecs, neigh, W, out, n_tiles);
}

// Round 17
// 191.618 us; speedup vs baseline: 2.9784x; 1.0786x over previous
//
#include <hip/hip_runtime.h>

// GAT aggregate, FUSED (R17 = R16 + lane-packed ctx): N=100000, K=16, D=128,
// DOUT=128, fp32. Per 16-node tile, one 512-thr block (8 waves). Each wave
// computes TWO ctx rows SIMULTANEOUSLY: node A in lanes 0-31, node B in lanes
// 32-63, 4 dims/lane (float4). Butterfly shfl_xor(1..16) stays inside each
// 32-lane half -> both nodes' 17 score reductions share the same 85 shfl ops
// (2.4x DS-pipe cut vs R16; DS-issue is the measured wall: R15/R16 showed HBM
// hidden, all pipes <30%, occupancy-doubling null). Two-pass softmax, fp32 --
// numerics identical to R13-R16 (absmax 0.03125). MFMA epilogue R16-verbatim.

constexpr int K    = 16;
constexpr int D    = 128;
constexpr int DOUT = 128;
constexpr int WT_PITCH = 136;   // bf16 Wt pitch (shorts), 272B rows
constexpr int CT_PITCH = 132;   // f32 Ct pitch (floats), 528B rows (16B-aligned)

typedef short bfrag  __attribute__((ext_vector_type(8)));
typedef float afrag  __attribute__((ext_vector_type(4)));

__device__ __forceinline__ unsigned short f2bf(float f) {
    union { float f; unsigned u; } v; v.f = f;
    const unsigned r = v.u + 0x7FFF + ((v.u >> 16) & 1);   // RNE
    return (unsigned short)(r >> 16);
}
__device__ __forceinline__ float bf2f(unsigned short b) {
    union { unsigned u; float f; } v; v.u = ((unsigned)b) << 16;
    return v.f;
}

// 5-hop butterfly: allreduce WITHIN each 32-lane half (off<=16 never crosses bit 5)
__device__ __forceinline__ float half_allsum(float x) {
    #pragma unroll
    for (int off = 1; off <= 16; off <<= 1)
        x += __shfl_xor(x, off);
    return x;
}

__launch_bounds__(512, 2)
__global__ void gat_fused(const float* __restrict__ self_vecs,
                          const float* __restrict__ neigh_vecs,
                          const float* __restrict__ W,
                          float* __restrict__ out,
                          int n_tiles) {
    __shared__ __align__(16) unsigned short Wt[DOUT][WT_PITCH];   // 34.8 KiB
    __shared__ __align__(16) float Ct[2][16][CT_PITCH];           // 16.5 KiB

    const int tid = threadIdx.x;

    // ---- stage W^T as bf16 (R10-verbatim) ----
    for (int e = tid; e < D * DOUT; e += blockDim.x) {
        const int k = e >> 7, m = e & 127;     // W row-major [k][dout]
        Wt[m][k] = f2bf(W[e]);
    }
    __syncthreads();

    const int lane = tid & 63;
    const int wid  = tid >> 6;    // 0..7
    const int half = lane >> 5;   // 0: node r0, 1: node r0+1
    const int q    = lane & 31;   // owns dims 4q..4q+3
    const int nl   = lane & 15;
    const int kb   = lane >> 4;
    const int r0   = wid * 2;     // this wave's 2 rows in the tile

    float4 v[K], sv;              // packed: this lane's node = r0+half

    int buf = 0;
    int t = blockIdx.x;

    // prologue: load both nodes (lane half selects the node; 2x512B per instr)
    if (t < n_tiles) {
        const int n0 = t * 16 + r0 + half;
        const float4* nb = (const float4*)(neigh_vecs + (size_t)n0 * (K * D)) + q;
        #pragma unroll
        for (int k = 0; k < K; ++k) v[k] = nb[k * 32];
        sv = ((const float4*)(self_vecs + (size_t)n0 * D))[q];
    }

    for (; t < n_tiles; t += gridDim.x, buf ^= 1) {
        const int node0 = t * 16;

        // ---- pass 1: 17 independent dot reductions (both nodes at once) ----
        float ss = sv.x * sv.x + sv.y * sv.y + sv.z * sv.z + sv.w * sv.w;
        float sc[K];
        #pragma unroll
        for (int k = 0; k < K; ++k)
            sc[k] = sv.x * v[k].x + sv.y * v[k].y + sv.z * v[k].z + sv.w * v[k].w;
        ss = half_allsum(ss);
        #pragma unroll
        for (int k = 0; k < K; ++k) sc[k] = half_allsum(sc[k]);

        // ---- pass 2: stable softmax + weighted sum (fp32, R13 numerics) ----
        float m = ss;
        #pragma unroll
        for (int k = 0; k < K; ++k) m = fmaxf(m, sc[k]);
        float e   = __expf(ss - m);
        float sum = e;
        float4 cx = make_float4(e * sv.x, e * sv.y, e * sv.z, e * sv.w);
        #pragma unroll
        for (int k = 0; k < K; ++k) {
            const float ek = __expf(sc[k] - m);
            sum += ek;
            cx.x += ek * v[k].x; cx.y += ek * v[k].y;
            cx.z += ek * v[k].z; cx.w += ek * v[k].w;
        }
        const float inv = 1.f / sum;
        *(float4*)&Ct[buf][r0 + half][4 * q] =
            make_float4(cx.x * inv, cx.y * inv, cx.z * inv, cx.w * inv);

        // ---- prefetch next tile into v/sv (regs dead; loads drain during MFMA) ----
        const int tn = t + gridDim.x;
        if (tn < n_tiles) {
            const int n0 = tn * 16 + r0 + half;
            const float4* nb = (const float4*)(neigh_vecs + (size_t)n0 * (K * D)) + q;
            #pragma unroll
            for (int k = 0; k < K; ++k) v[k] = nb[k * 32];
            sv = ((const float4*)(self_vecs + (size_t)n0 * D))[q];
        }

        __syncthreads();   // Ct[buf] complete (dbuf -> only barrier per tile)

        // ---- MFMA (R16-verbatim): this wave does nt = wid ----
        afrag acc;
        #pragma unroll
        for (int r4 = 0; r4 < 4; ++r4) acc[r4] = 0.f;

        #pragma unroll
        for (int kc = 0; kc < 4; ++kc) {
            const float* cp = &Ct[buf][nl][kc * 32 + kb * 8];
            const float4 c0 = *(const float4*)cp;
            const float4 c1 = *(const float4*)(cp + 4);
            const float cf[8] = {c0.x, c0.y, c0.z, c0.w, c1.x, c1.y, c1.z, c1.w};
            bfrag ch, cl;
            #pragma unroll
            for (int i = 0; i < 8; ++i) {
                const unsigned short hh = f2bf(cf[i]);
                ch[i] = (short)hh;
                cl[i] = (short)f2bf(cf[i] - bf2f(hh));
            }
            const bfrag a = *(const bfrag*)&Wt[wid * 16 + nl][kc * 32 + kb * 8];
            acc = __builtin_amdgcn_mfma_f32_16x16x32_bf16(a, ch, acc, 0, 0, 0);
            acc = __builtin_amdgcn_mfma_f32_16x16x32_bf16(a, cl, acc, 0, 0, 0);
        }
        // D: col=lane&15=node, row=(lane>>4)*4+r=outcol (m89-verified)
        float* orow = out + (size_t)(node0 + nl) * DOUT + kb * 4;
        *(float4*)(orow + wid * 16) =
            make_float4(fmaxf(acc[0], 0.f), fmaxf(acc[1], 0.f),
                        fmaxf(acc[2], 0.f), fmaxf(acc[3], 0.f));
    }
}

extern "C" void kernel_launch(void* const* d_in, const int* in_sizes, int n_in,
                              void* d_out, int out_size, void* d_ws, size_t ws_size,
                              hipStream_t stream) {
    const float* self_vecs = (const float*)d_in[0];
    const float* neigh     = (const float*)d_in[1];
    const float* W         = (const float*)d_in[2];
    float* out = (float*)d_out;

    const int n_nodes = in_sizes[0] / D;   // 100000
    const int n_tiles = n_nodes / 16;      // 6250 exact

    const int tpb = 512;     // 8 waves
    const int blocks = 512;  // 2 blocks/CU x 256 CU -> 16 waves/CU, VGPR cap 128
    gat_fused<<<dim3(blocks), dim3(tpb), 0, stream>>>(
        self_vecs, neigh, W, out, n_tiles);
}